// Round 5
// baseline (241.557 us; speedup 1.0000x reference)
//
#include <hip/hip_runtime.h>

// Path signature depth 5, d=10, L=128, B=256 — MFMA, fused + 2 blocks/CU.
//
// Same verified algebra as rounds 2-3: per batch a [1000 x 254] x [254 x 110]
// GEMM (K = 2 terms/segment: W1*d[c4]*R[e] + W0h*d[c4]*d[e]; level-4 rides as
// aug cols 100..109), fp32 accuracy via 2-way bf16 split, 4 cross MFMAs.
//
// Geometry: block M = 128 rows (8 blocks/batch, grid 2048). LDS = 72000 B ->
// TWO resident blocks/CU (16 waves): cross-BLOCK overlap fills the scan
// waves' serial-chain + barrier-skew gaps (independent barrier groups).
// NOTE: no min-waves launch_bounds cap — round 4's failure is attributed to
// the 128-VGPR cap forcing spills around the tied-accumulator MFMAs; this
// structure needs only ~75 live VGPRs (per-nt B loads; only ah/al + acc[7]
// live across produce), so the natural allocation stays under 128.

#define D10    10
#define LPATH  128
#define NSEG   127
#define BLOCK  512
#define NROW   128     // panel rows per block (125 active)
#define NROWA  125
#define NCOL   112     // 100 level5 cols + 10 level4-aug + 2 pad
#define NCOLA  110
#define KC     16      // segments per chunk -> K = 32 bf16
#define NCH    8       // 8*16 = 128 >= 127 (u=127 zero pad)
#define SD     132     // dTT/RT row stride (floats, rows 16B-aligned)
#define OUT_PER_B 111110

typedef __attribute__((ext_vector_type(8))) short bf16x8;
typedef __attribute__((ext_vector_type(4))) float f32x4;

// pack bf16(x),bf16(y) (truncation) into hi word; packed residuals into lo.
__device__ __forceinline__ unsigned pack_split(float x, float y, unsigned &lo)
{
    unsigned xb = __float_as_uint(x), yb = __float_as_uint(y);
    float xr = x - __uint_as_float(xb & 0xffff0000u);
    float yr = y - __uint_as_float(yb & 0xffff0000u);
    lo = (__float_as_uint(xr) >> 16) | (__float_as_uint(yr) & 0xffff0000u);
    return (xb >> 16) | (yb & 0xffff0000u);
}

__global__ __launch_bounds__(BLOCK) void sig_kernel(
        const float* __restrict__ path,   // [B][D10][LPATH]
        float* __restrict__ out)          // [B][OUT_PER_B]
{
    __shared__ __align__(16) float dTT[D10 * SD];          // d_u[c]
    __shared__ __align__(16) float RT [D10 * SD];          // R_u[c] suffix
    __shared__ __align__(16) short AhiS[2][4 * NROW * 8];  // [buf][kg][row][8]
    __shared__ __align__(16) short AloS[2][4 * NROW * 8];
    __shared__ __align__(16) short BhiS[2][4 * NCOL * 8];  // [buf][kg][col][8]
    __shared__ __align__(16) short BloS[2][4 * NCOL * 8];

    const int tid = threadIdx.x;
    const int bb  = blockIdx.x;
    const int b   = bb >> 3;
    const int q   = bb & 7;                 // 125-row slice of the 1000 rows
    const float* pb = path + (size_t)b * (D10 * LPATH);

    // ---- delta + suffix tables (R telescopes; t>=NSEG zero-padded) ----
    for (int idx = tid; idx < D10 * SD; idx += BLOCK) {
        int c = idx / SD, t = idx - c * SD;
        float d = 0.f, r = 0.f;
        if (t < NSEG) {
            float p1 = pb[c * LPATH + t + 1];
            d = p1 - pb[c * LPATH + t];
            r = pb[c * LPATH + NSEG] - p1;
        }
        dTT[idx] = d;
        RT [idx] = r;
    }
    // zero pad A rows 125..127 (both buffers, all k-groups) once
    for (int idx = tid; idx < 2 * 4 * (NROW - NROWA) * 8; idx += BLOCK) {
        int bufi = idx / (4 * (NROW - NROWA) * 8);
        int rem  = idx - bufi * (4 * (NROW - NROWA) * 8);
        int kg   = rem / ((NROW - NROWA) * 8);
        int rr   = rem - kg * ((NROW - NROWA) * 8);
        int o = (kg * NROW + NROWA) * 8 + rr;
        AhiS[bufi][o] = 0; AloS[bufi][o] = 0;
    }
    // zero pad B cols 110..111 (both buffers) once
    if (tid < 2 * 4 * 2 * 8) {              // 128 threads
        int bufi = tid >> 6;
        int rem  = tid & 63;
        int kg   = rem >> 4;
        int rr   = rem & 15;
        int o = (kg * NCOL + NCOLA) * 8 + rr;
        BhiS[bufi][o] = 0; BloS[bufi][o] = 0;
    }

    // ---- scan identity (threads < 125): row = q*125 + tid ----
    const int grow = q * NROWA + tid;
    const int g   = grow / 100;
    const int m3  = grow - g * 100;
    const int c2  = m3 / 10;
    const int c3  = m3 - c2 * 10;
    const int goff = g * SD, c2off = c2 * SD, c3off = c3 * SD;

    const int lane = tid & 63;
    const int wv   = tid >> 6;      // 8 waves; wave owns rows [wv*16, wv*16+16)
    const int rl   = lane & 15;
    const int kgl  = lane >> 4;

    float s1 = 0.f, s2 = 0.f, s3 = 0.f;
    f32x4 acc[7];
#pragma unroll
    for (int nt = 0; nt < 7; ++nt) acc[nt] = f32x4{0.f, 0.f, 0.f, 0.f};

    // produce chunk (kc0) into buffer pp. Scan on tid<125 (waves 0-1);
    // B-build on tid>=128 (waves 2-7, 384 threads for 440 items).
    auto produce = [&](int pp, int kc0) {
        if (tid < NROWA) {
#pragma unroll
            for (int w0 = 0; w0 < KC; w0 += 4) {
                float4 g4 = *(const float4*)&dTT[goff  + kc0 + w0];
                float4 a4 = *(const float4*)&dTT[c2off + kc0 + w0];
                float4 b4 = *(const float4*)&dTT[c3off + kc0 + w0];
                float ga[4] = {g4.x, g4.y, g4.z, g4.w};
                float aa[4] = {a4.x, a4.y, a4.z, a4.w};
                float ba[4] = {b4.x, b4.y, b4.z, b4.w};
                unsigned hw[4], lw[4];
#pragma unroll
                for (int j = 0; j < 4; ++j) {
                    float dg = ga[j], d2 = aa[j], d3 = ba[j];
                    float u24 = s2 + (s1 + dg * 0.25f)     * d2 * (1.f / 3.f);
                    float u25 = s2 + (s1 + dg * 0.2f)      * d2 * 0.25f;
                    float u23 = s2 + (s1 + dg * (1.f/3.f)) * d2 * 0.5f;
                    float w1v = s3 + u24 * d3 * 0.5f;
                    float w0h = 0.5f * (s3 + u25 * d3 * (1.f / 3.f));
                    s3 += u23 * d3;
                    s2 += (s1 + dg * 0.5f) * d2;
                    s1 += dg;                     // d=0 pads leave state fixed
                    hw[j] = pack_split(w1v, w0h, lw[j]);  // k=2u: W1, 2u+1: W0h
                }
                const int ai = ((w0 >> 2) * NROW + tid) * 8;
                *(uint4*)&AhiS[pp][ai] = make_uint4(hw[0], hw[1], hw[2], hw[3]);
                *(uint4*)&AloS[pp][ai] = make_uint4(lw[0], lw[1], lw[2], lw[3]);
            }
        } else if (tid >= 128) {
            for (int s = tid - 128; s < 4 * NCOLA; s += 384) {
                const int cb  = s >> 2;         // col 0..109
                const int kgB = s & 3;
                int c4o, ebo = 0;
                if (cb < 100) { int c4 = cb / 10; ebo = (cb - c4 * 10) * SD; c4o = c4 * SD; }
                else          { c4o = (cb - 100) * SD; }
                const int u0 = kc0 + kgB * 4;
                float4 d4 = *(const float4*)&dTT[c4o + u0];
                float da[4] = {d4.x, d4.y, d4.z, d4.w};
                unsigned hw[4], lw[4];
                if (cb < 100) {
                    float4 e4 = *(const float4*)&dTT[ebo + u0];
                    float4 r4 = *(const float4*)&RT [ebo + u0];
                    float ea[4] = {e4.x, e4.y, e4.z, e4.w};
                    float ra[4] = {r4.x, r4.y, r4.z, r4.w};
#pragma unroll
                    for (int j = 0; j < 4; ++j)
                        hw[j] = pack_split(da[j] * ra[j], da[j] * ea[j], lw[j]);
                } else {        // level-4 aug cols: B1 = d, B0 = 0
#pragma unroll
                    for (int j = 0; j < 4; ++j)
                        hw[j] = pack_split(da[j], 0.f, lw[j]);
                }
                const int bi = (kgB * NCOL + cb) * 8;
                *(uint4*)&BhiS[pp][bi] = make_uint4(hw[0], hw[1], hw[2], hw[3]);
                *(uint4*)&BloS[pp][bi] = make_uint4(lw[0], lw[1], lw[2], lw[3]);
            }
        }
    };

    __syncthreads();                 // tables + pads ready
    produce(0, 0);
    __syncthreads();                 // buf0 ready

    for (int ch = 0; ch < NCH; ++ch) {
        const int p = ch & 1;
        // ---- A-fragment loads for chunk ch (round-3 order: loads first) ----
        const int ai = (kgl * NROW + wv * 16 + rl) * 8;
        bf16x8 ah = *(const bf16x8*)&AhiS[p][ai];
        bf16x8 al = *(const bf16x8*)&AloS[p][ai];
        // ---- produce chunk ch+1 into the other buffer ----
        if (ch + 1 < NCH) produce(p ^ 1, (ch + 1) * KC);
        // ---- 1 M-tile x 7 N-tiles x 4 split-term MFMAs (B loaded per-nt) ----
#pragma unroll
        for (int nt = 0; nt < 7; ++nt) {
            const int bi = (kgl * NCOL + nt * 16 + rl) * 8;
            bf16x8 bh = *(const bf16x8*)&BhiS[p][bi];
            bf16x8 bl = *(const bf16x8*)&BloS[p][bi];
            acc[nt] = __builtin_amdgcn_mfma_f32_16x16x32_bf16(ah, bh, acc[nt], 0, 0, 0);
            acc[nt] = __builtin_amdgcn_mfma_f32_16x16x32_bf16(ah, bl, acc[nt], 0, 0, 0);
            acc[nt] = __builtin_amdgcn_mfma_f32_16x16x32_bf16(al, bh, acc[nt], 0, 0, 0);
            acc[nt] = __builtin_amdgcn_mfma_f32_16x16x32_bf16(al, bl, acc[nt], 0, 0, 0);
        }
        __syncthreads();             // buf[p^1] written; buf[p] reads done
    }

    // ---- epilogue (registers only; no barrier) ----
    float* ob = out + (size_t)b * OUT_PER_B;
    if (tid < NROWA) {
        ob[110 + grow] = s3;                       // level 3
        if (c3 == 0) ob[10 + g * 10 + c2] = s2;    // level 2
        if (m3 == 0) ob[g] = s1;                   // level 1
    }
    // D layout (m89-verified): col = lane&15, row = (lane>>4)*4 + reg
#pragma unroll
    for (int r = 0; r < 4; ++r) {
        const int prow = wv * 16 + kgl * 4 + r;
        if (prow < NROWA) {
            const int gr = q * NROWA + prow;
#pragma unroll
            for (int nt = 0; nt < 7; ++nt) {
                const int col = nt * 16 + rl;
                const float v = acc[nt][r];
                if (col < 100)
                    ob[11110 + (size_t)gr * 100 + col] = v;   // level 5
                else if (col < NCOLA)
                    ob[1110 + gr * 10 + (col - 100)] = v;     // level 4
            }
        }
    }
}

extern "C" void kernel_launch(void* const* d_in, const int* in_sizes, int n_in,
                              void* d_out, int out_size, void* d_ws, size_t ws_size,
                              hipStream_t stream) {
    const float* path = (const float*)d_in[0];
    float* out = (float*)d_out;
    int B = in_sizes[0] / (D10 * LPATH);   // 256
    sig_kernel<<<B * 8, BLOCK, 0, stream>>>(path, out);
}

// Round 8
// 190.782 us; speedup vs baseline: 1.2661x; 1.2661x over previous
//
#include <hip/hip_runtime.h>

// Path signature depth 5, d=10, L=128, B=256 — MFMA, fused produce/consume.
// Base = round-3 kernel (110 µs, PASSED) with three minimal, independently
// safe changes:
//   1. B kg-plane stride padded 112 -> 113 (NCOLP): buildB's uint4 writes had
//      kgB-stride 1792B = bank 0 -> 4-way bank conflict (3.86M counted);
//      stride 1808B puts kgB planes on banks 0/4/8/12 -> conflict-free.
//   2. al*bl MFMA term dropped (contribution ~2^-16 relative, negligible vs
//      threshold): 56 -> 42 MFMAs per chunk-wave.
//   3. s_setprio(1) around the scan body: the serial scan chain is the
//      measured critical path (~2000 cyc/chunk); priority biases CU issue
//      toward scan waves while MFMA/B-build waves fill the gaps (T5).
// Everything else byte-identical to round 3: [1000 x 254] x [254 x 110] GEMM
// per batch, fp32 via 2-way bf16 split, A/B double-buffered, ONE barrier per
// chunk, 4 blocks/batch (q = 250-row slice), 512 threads.

#define D10    10
#define LPATH  128
#define NSEG   127
#define BLOCK  512
#define NROW   256     // panel rows per block (250 active)
#define NROWA  250
#define NCOL   112     // 100 level5 cols + 10 level4-aug + 2 pad
#define NCOLP  113     // padded kg-plane stride (bank de-conflict)
#define NCOLA  110
#define KC     16      // segments per chunk -> K = 32 bf16
#define NCH    8       // 8*16 = 128 >= 127 (u=127 zero pad)
#define SD     132     // dTT/RT row stride (floats)
#define OUT_PER_B 111110

typedef __attribute__((ext_vector_type(8))) short bf16x8;
typedef __attribute__((ext_vector_type(4))) float f32x4;

// pack bf16(x),bf16(y) (truncation) into hi word; packed residuals into lo.
__device__ __forceinline__ unsigned pack_split(float x, float y, unsigned &lo)
{
    unsigned xb = __float_as_uint(x), yb = __float_as_uint(y);
    float xr = x - __uint_as_float(xb & 0xffff0000u);
    float yr = y - __uint_as_float(yb & 0xffff0000u);
    lo = (__float_as_uint(xr) >> 16) | (__float_as_uint(yr) & 0xffff0000u);
    return (xb >> 16) | (yb & 0xffff0000u);
}

__global__ __launch_bounds__(BLOCK, 1) void sig_kernel(
        const float* __restrict__ path,   // [B][D10][LPATH]
        float* __restrict__ out)          // [B][OUT_PER_B]
{
    __shared__ __align__(16) float dTT[D10 * SD];          // d_u[c]
    __shared__ __align__(16) float RT [D10 * SD];          // R_u[c] suffix
    __shared__ __align__(16) short AhiS[2][4 * NROW * 8];  // [buf][kg][row][8]
    __shared__ __align__(16) short AloS[2][4 * NROW * 8];
    __shared__ __align__(16) short BhiS[2][4 * NCOLP * 8]; // [buf][kg][col][8]
    __shared__ __align__(16) short BloS[2][4 * NCOLP * 8];

    const int tid = threadIdx.x;
    const int bb  = blockIdx.x;
    const int b   = bb >> 2;
    const int q   = bb & 3;                 // 250-row slice of the 1000 rows
    const float* pb = path + (size_t)b * (D10 * LPATH);

    // ---- delta + suffix tables (R telescopes; t>=NSEG zero-padded) ----
    for (int idx = tid; idx < D10 * SD; idx += BLOCK) {
        int c = idx / SD, t = idx - c * SD;
        float d = 0.f, r = 0.f;
        if (t < NSEG) {
            float p1 = pb[c * LPATH + t + 1];
            d = p1 - pb[c * LPATH + t];
            r = pb[c * LPATH + NSEG] - p1;
        }
        dTT[idx] = d;
        RT [idx] = r;
    }
    // zero pad A rows 250..255 (both buffers, all k-groups) once
    for (int idx = tid; idx < 2 * 4 * (NROW - NROWA) * 8; idx += BLOCK) {
        int bufi = idx / (4 * 6 * 8);
        int rem  = idx - bufi * (4 * 6 * 8);
        int kg   = rem / (6 * 8);
        int rr   = rem - kg * (6 * 8);
        int o = (kg * NROW + NROWA) * 8 + rr;
        AhiS[bufi][o] = 0; AloS[bufi][o] = 0;
    }
    // zero pad B cols 110..111 (both buffers) once
    if (tid < 2 * 4 * 2 * 8) {
        int bufi = tid >> 6;
        int rem  = tid & 63;
        int kg   = rem >> 4;
        int rr   = rem & 15;
        int o = (kg * NCOLP + NCOLA) * 8 + rr;
        BhiS[bufi][o] = 0; BloS[bufi][o] = 0;
    }

    // ---- scan identity (threads < 250): row = q*250 + tid ----
    const int grow = q * NROWA + tid;
    const int g   = grow / 100;
    const int m3  = grow - g * 100;
    const int c2  = m3 / 10;
    const int c3  = m3 - c2 * 10;
    const int goff = g * SD, c2off = c2 * SD, c3off = c3 * SD;

    const int lane = tid & 63;
    const int wv   = tid >> 6;      // 8 waves x 32 rows each
    const int rl   = lane & 15;
    const int kgl  = lane >> 4;

    float s1 = 0.f, s2 = 0.f, s3 = 0.f;
    f32x4 acc[2][7];
#pragma unroll
    for (int i = 0; i < 2; ++i)
#pragma unroll
        for (int nt = 0; nt < 7; ++nt) acc[i][nt] = f32x4{0.f, 0.f, 0.f, 0.f};

    // produce chunk (kc0) into buffer pp. Scan on waves 0-3; B-build on
    // waves 4-7 (disjoint waves -> co-schedulable with consume MFMAs).
    auto produce = [&](int pp, int kc0) {
        if (tid < NROWA) {
            __builtin_amdgcn_s_setprio(1);   // scan = critical serial chain
#pragma unroll
            for (int w0 = 0; w0 < KC; w0 += 4) {
                float4 g4 = *(const float4*)&dTT[goff  + kc0 + w0];
                float4 a4 = *(const float4*)&dTT[c2off + kc0 + w0];
                float4 b4 = *(const float4*)&dTT[c3off + kc0 + w0];
                float ga[4] = {g4.x, g4.y, g4.z, g4.w};
                float aa[4] = {a4.x, a4.y, a4.z, a4.w};
                float ba[4] = {b4.x, b4.y, b4.z, b4.w};
                unsigned hw[4], lw[4];
#pragma unroll
                for (int j = 0; j < 4; ++j) {
                    float dg = ga[j], d2 = aa[j], d3 = ba[j];
                    float u24 = s2 + (s1 + dg * 0.25f)     * d2 * (1.f / 3.f);
                    float u25 = s2 + (s1 + dg * 0.2f)      * d2 * 0.25f;
                    float u23 = s2 + (s1 + dg * (1.f/3.f)) * d2 * 0.5f;
                    float w1v = s3 + u24 * d3 * 0.5f;
                    float w0h = 0.5f * (s3 + u25 * d3 * (1.f / 3.f));
                    s3 += u23 * d3;
                    s2 += (s1 + dg * 0.5f) * d2;
                    s1 += dg;                     // d=0 pads leave state fixed
                    hw[j] = pack_split(w1v, w0h, lw[j]);  // k=2u: W1, 2u+1: W0h
                }
                const int ai = ((w0 >> 2) * NROW + tid) * 8;
                *(uint4*)&AhiS[pp][ai] = make_uint4(hw[0], hw[1], hw[2], hw[3]);
                *(uint4*)&AloS[pp][ai] = make_uint4(lw[0], lw[1], lw[2], lw[3]);
            }
            __builtin_amdgcn_s_setprio(0);
        } else if (tid >= 256) {
            for (int s = tid - 256; s < 4 * NCOLA; s += 256) {
                const int cb  = s >> 2;         // col 0..109
                const int kgB = s & 3;
                int c4o, ebo = 0;
                if (cb < 100) { int c4 = cb / 10; ebo = (cb - c4 * 10) * SD; c4o = c4 * SD; }
                else          { c4o = (cb - 100) * SD; }
                const int u0 = kc0 + kgB * 4;
                float4 d4 = *(const float4*)&dTT[c4o + u0];
                float da[4] = {d4.x, d4.y, d4.z, d4.w};
                unsigned hw[4], lw[4];
                if (cb < 100) {
                    float4 e4 = *(const float4*)&dTT[ebo + u0];
                    float4 r4 = *(const float4*)&RT [ebo + u0];
                    float ea[4] = {e4.x, e4.y, e4.z, e4.w};
                    float ra[4] = {r4.x, r4.y, r4.z, r4.w};
#pragma unroll
                    for (int j = 0; j < 4; ++j)
                        hw[j] = pack_split(da[j] * ra[j], da[j] * ea[j], lw[j]);
                } else {        // level-4 aug cols: B1 = d, B0 = 0
#pragma unroll
                    for (int j = 0; j < 4; ++j)
                        hw[j] = pack_split(da[j], 0.f, lw[j]);
                }
                const int bi = (kgB * NCOLP + cb) * 8;
                *(uint4*)&BhiS[pp][bi] = make_uint4(hw[0], hw[1], hw[2], hw[3]);
                *(uint4*)&BloS[pp][bi] = make_uint4(lw[0], lw[1], lw[2], lw[3]);
            }
        }
    };

    __syncthreads();                 // tables + pads ready
    produce(0, 0);
    __syncthreads();                 // buf0 ready

    for (int ch = 0; ch < NCH; ++ch) {
        const int p = ch & 1;
        // ---- fragment loads for chunk ch (issue early, in-order LDS) ----
        bf16x8 bh[7], bl[7];
#pragma unroll
        for (int nt = 0; nt < 7; ++nt) {
            const int bi = (kgl * NCOLP + nt * 16 + rl) * 8;
            bh[nt] = *(const bf16x8*)&BhiS[p][bi];
            bl[nt] = *(const bf16x8*)&BloS[p][bi];
        }
        bf16x8 ah[2], al[2];
#pragma unroll
        for (int i = 0; i < 2; ++i) {
            const int ai = (kgl * NROW + wv * 32 + i * 16 + rl) * 8;
            ah[i] = *(const bf16x8*)&AhiS[p][ai];
            al[i] = *(const bf16x8*)&AloS[p][ai];
        }
        // ---- produce chunk ch+1 into the other buffer (overlaps MFMA) ----
        if (ch + 1 < NCH) produce(p ^ 1, (ch + 1) * KC);
        // ---- 2 M-tiles x 7 N-tiles x 3 split-term MFMAs (al*bl dropped:
        //      contribution ~2^-16 relative, far below threshold) ----
#pragma unroll
        for (int i = 0; i < 2; ++i)
#pragma unroll
            for (int nt = 0; nt < 7; ++nt) {
                acc[i][nt] = __builtin_amdgcn_mfma_f32_16x16x32_bf16(ah[i], bh[nt], acc[i][nt], 0, 0, 0);
                acc[i][nt] = __builtin_amdgcn_mfma_f32_16x16x32_bf16(ah[i], bl[nt], acc[i][nt], 0, 0, 0);
                acc[i][nt] = __builtin_amdgcn_mfma_f32_16x16x32_bf16(al[i], bh[nt], acc[i][nt], 0, 0, 0);
            }
        __syncthreads();             // buf[p^1] written; buf[p] reads done
    }

    // ---- epilogue (registers only; no barrier) ----
    float* ob = out + (size_t)b * OUT_PER_B;
    if (tid < NROWA) {
        ob[110 + grow] = s3;                       // level 3
        if (c3 == 0) ob[10 + g * 10 + c2] = s2;    // level 2
        if (m3 == 0) ob[g] = s1;                   // level 1
    }
    // D layout (m89-verified): col = lane&15, row = (lane>>4)*4 + reg
#pragma unroll
    for (int i = 0; i < 2; ++i) {
#pragma unroll
        for (int r = 0; r < 4; ++r) {
            const int prow = wv * 32 + i * 16 + kgl * 4 + r;
            if (prow < NROWA) {
                const int gr = q * NROWA + prow;
#pragma unroll
                for (int nt = 0; nt < 7; ++nt) {
                    const int col = nt * 16 + rl;
                    const float v = acc[i][nt][r];
                    if (col < 100)
                        ob[11110 + (size_t)gr * 100 + col] = v;   // level 5
                    else if (col < NCOLA)
                        ob[1110 + gr * 10 + (col - 100)] = v;     // level 4
                }
            }
        }
    }
}

extern "C" void kernel_launch(void* const* d_in, const int* in_sizes, int n_in,
                              void* d_out, int out_size, void* d_ws, size_t ws_size,
                              hipStream_t stream) {
    const float* path = (const float*)d_in[0];
    float* out = (float*)d_out;
    int B = in_sizes[0] / (D10 * LPATH);   // 256
    sig_kernel<<<B * 4, BLOCK, 0, stream>>>(path, out);
}

// Round 9
// 187.995 us; speedup vs baseline: 1.2849x; 1.0148x over previous
//
#include <hip/hip_runtime.h>

// Path signature depth 5, d=10, L=128, B=256 — MFMA, fused produce/consume.
// Base = round-3 kernel (110 µs, PASSED), with exactly ONE change:
//   * al*bl cross-term MFMA dropped (contribution ~2^-16 relative; measured
//     in round 8: absmax 4.0 -> 8.0, threshold 33.6). 56 -> 42 MFMAs per
//     chunk-wave = -25% MFMA-pipe time (per-SIMD 16x16x32 ~19 cyc, so the
//     MFMA pipe at 2 waves/SIMD is ~2.2k cyc/chunk — co-dominant with the
//     scan chain, worth cutting).
// Round 8's NCOLP pad (bank conflicts went UP) and scan setprio (m190-style
// regression risk) are reverted.
//
// Structure: per batch a [1000 x 254] x [254 x 110] GEMM (K = 2 terms per
// segment: W1*d[c4]*R[e] + W0h*d[c4]*d[e]; level-4 rides as aug cols
// 100..109), fp32 accuracy via 2-way bf16 split. A/B double-buffered,
// ONE barrier per chunk, produce(ch+1) fused into consume(ch) phase,
// 4 blocks/batch (q = 250-row slice), 512 threads, 1 block/CU.

#define D10    10
#define LPATH  128
#define NSEG   127
#define BLOCK  512
#define NROW   256     // panel rows per block (250 active)
#define NROWA  250
#define NCOL   112     // 100 level5 cols + 10 level4-aug + 2 pad
#define NCOLA  110
#define KC     16      // segments per chunk -> K = 32 bf16
#define NCH    8       // 8*16 = 128 >= 127 (u=127 zero pad)
#define SD     132     // dTT/RT row stride (floats)
#define OUT_PER_B 111110

typedef __attribute__((ext_vector_type(8))) short bf16x8;
typedef __attribute__((ext_vector_type(4))) float f32x4;

// pack bf16(x),bf16(y) (truncation) into hi word; packed residuals into lo.
__device__ __forceinline__ unsigned pack_split(float x, float y, unsigned &lo)
{
    unsigned xb = __float_as_uint(x), yb = __float_as_uint(y);
    float xr = x - __uint_as_float(xb & 0xffff0000u);
    float yr = y - __uint_as_float(yb & 0xffff0000u);
    lo = (__float_as_uint(xr) >> 16) | (__float_as_uint(yr) & 0xffff0000u);
    return (xb >> 16) | (yb & 0xffff0000u);
}

__global__ __launch_bounds__(BLOCK, 1) void sig_kernel(
        const float* __restrict__ path,   // [B][D10][LPATH]
        float* __restrict__ out)          // [B][OUT_PER_B]
{
    __shared__ __align__(16) float dTT[D10 * SD];          // d_u[c]
    __shared__ __align__(16) float RT [D10 * SD];          // R_u[c] suffix
    __shared__ __align__(16) short AhiS[2][4 * NROW * 8];  // [buf][kg][row][8]
    __shared__ __align__(16) short AloS[2][4 * NROW * 8];
    __shared__ __align__(16) short BhiS[2][4 * NCOL * 8];  // [buf][kg][col][8]
    __shared__ __align__(16) short BloS[2][4 * NCOL * 8];

    const int tid = threadIdx.x;
    const int bb  = blockIdx.x;
    const int b   = bb >> 2;
    const int q   = bb & 3;                 // 250-row slice of the 1000 rows
    const float* pb = path + (size_t)b * (D10 * LPATH);

    // ---- delta + suffix tables (R telescopes; t>=NSEG zero-padded) ----
    for (int idx = tid; idx < D10 * SD; idx += BLOCK) {
        int c = idx / SD, t = idx - c * SD;
        float d = 0.f, r = 0.f;
        if (t < NSEG) {
            float p1 = pb[c * LPATH + t + 1];
            d = p1 - pb[c * LPATH + t];
            r = pb[c * LPATH + NSEG] - p1;
        }
        dTT[idx] = d;
        RT [idx] = r;
    }
    // zero pad A rows 250..255 (both buffers, all k-groups) once
    for (int idx = tid; idx < 2 * 4 * (NROW - NROWA) * 8; idx += BLOCK) {
        int bufi = idx / (4 * 6 * 8);
        int rem  = idx - bufi * (4 * 6 * 8);
        int kg   = rem / (6 * 8);
        int rr   = rem - kg * (6 * 8);
        int o = (kg * NROW + NROWA) * 8 + rr;
        AhiS[bufi][o] = 0; AloS[bufi][o] = 0;
    }
    // zero pad B cols 110..111 (both buffers) once
    if (tid < 2 * 4 * 2 * 8) {
        int bufi = tid >> 6;
        int rem  = tid & 63;
        int kg   = rem >> 4;
        int rr   = rem & 15;
        int o = (kg * NCOL + NCOLA) * 8 + rr;
        BhiS[bufi][o] = 0; BloS[bufi][o] = 0;
    }

    // ---- scan identity (threads < 250): row = q*250 + tid ----
    const int grow = q * NROWA + tid;
    const int g   = grow / 100;
    const int m3  = grow - g * 100;
    const int c2  = m3 / 10;
    const int c3  = m3 - c2 * 10;
    const int goff = g * SD, c2off = c2 * SD, c3off = c3 * SD;

    const int lane = tid & 63;
    const int wv   = tid >> 6;      // 8 waves x 32 rows each
    const int rl   = lane & 15;
    const int kgl  = lane >> 4;

    float s1 = 0.f, s2 = 0.f, s3 = 0.f;
    f32x4 acc[2][7];
#pragma unroll
    for (int i = 0; i < 2; ++i)
#pragma unroll
        for (int nt = 0; nt < 7; ++nt) acc[i][nt] = f32x4{0.f, 0.f, 0.f, 0.f};

    // produce chunk (kc0) into buffer pp. Scan on waves 0-3; B-build on
    // waves 4-7 (disjoint waves -> co-schedulable with consume MFMAs).
    auto produce = [&](int pp, int kc0) {
        if (tid < NROWA) {
#pragma unroll
            for (int w0 = 0; w0 < KC; w0 += 4) {
                float4 g4 = *(const float4*)&dTT[goff  + kc0 + w0];
                float4 a4 = *(const float4*)&dTT[c2off + kc0 + w0];
                float4 b4 = *(const float4*)&dTT[c3off + kc0 + w0];
                float ga[4] = {g4.x, g4.y, g4.z, g4.w};
                float aa[4] = {a4.x, a4.y, a4.z, a4.w};
                float ba[4] = {b4.x, b4.y, b4.z, b4.w};
                unsigned hw[4], lw[4];
#pragma unroll
                for (int j = 0; j < 4; ++j) {
                    float dg = ga[j], d2 = aa[j], d3 = ba[j];
                    float u24 = s2 + (s1 + dg * 0.25f)     * d2 * (1.f / 3.f);
                    float u25 = s2 + (s1 + dg * 0.2f)      * d2 * 0.25f;
                    float u23 = s2 + (s1 + dg * (1.f/3.f)) * d2 * 0.5f;
                    float w1v = s3 + u24 * d3 * 0.5f;
                    float w0h = 0.5f * (s3 + u25 * d3 * (1.f / 3.f));
                    s3 += u23 * d3;
                    s2 += (s1 + dg * 0.5f) * d2;
                    s1 += dg;                     // d=0 pads leave state fixed
                    hw[j] = pack_split(w1v, w0h, lw[j]);  // k=2u: W1, 2u+1: W0h
                }
                const int ai = ((w0 >> 2) * NROW + tid) * 8;
                *(uint4*)&AhiS[pp][ai] = make_uint4(hw[0], hw[1], hw[2], hw[3]);
                *(uint4*)&AloS[pp][ai] = make_uint4(lw[0], lw[1], lw[2], lw[3]);
            }
        } else if (tid >= 256) {
            for (int s = tid - 256; s < 4 * NCOLA; s += 256) {
                const int cb  = s >> 2;         // col 0..109
                const int kgB = s & 3;
                int c4o, ebo = 0;
                if (cb < 100) { int c4 = cb / 10; ebo = (cb - c4 * 10) * SD; c4o = c4 * SD; }
                else          { c4o = (cb - 100) * SD; }
                const int u0 = kc0 + kgB * 4;
                float4 d4 = *(const float4*)&dTT[c4o + u0];
                float da[4] = {d4.x, d4.y, d4.z, d4.w};
                unsigned hw[4], lw[4];
                if (cb < 100) {
                    float4 e4 = *(const float4*)&dTT[ebo + u0];
                    float4 r4 = *(const float4*)&RT [ebo + u0];
                    float ea[4] = {e4.x, e4.y, e4.z, e4.w};
                    float ra[4] = {r4.x, r4.y, r4.z, r4.w};
#pragma unroll
                    for (int j = 0; j < 4; ++j)
                        hw[j] = pack_split(da[j] * ra[j], da[j] * ea[j], lw[j]);
                } else {        // level-4 aug cols: B1 = d, B0 = 0
#pragma unroll
                    for (int j = 0; j < 4; ++j)
                        hw[j] = pack_split(da[j], 0.f, lw[j]);
                }
                const int bi = (kgB * NCOL + cb) * 8;
                *(uint4*)&BhiS[pp][bi] = make_uint4(hw[0], hw[1], hw[2], hw[3]);
                *(uint4*)&BloS[pp][bi] = make_uint4(lw[0], lw[1], lw[2], lw[3]);
            }
        }
    };

    __syncthreads();                 // tables + pads ready
    produce(0, 0);
    __syncthreads();                 // buf0 ready

    for (int ch = 0; ch < NCH; ++ch) {
        const int p = ch & 1;
        // ---- fragment loads for chunk ch (issue early, in-order LDS) ----
        bf16x8 bh[7], bl[7];
#pragma unroll
        for (int nt = 0; nt < 7; ++nt) {
            const int bi = (kgl * NCOL + nt * 16 + rl) * 8;
            bh[nt] = *(const bf16x8*)&BhiS[p][bi];
            bl[nt] = *(const bf16x8*)&BloS[p][bi];
        }
        bf16x8 ah[2], al[2];
#pragma unroll
        for (int i = 0; i < 2; ++i) {
            const int ai = (kgl * NROW + wv * 32 + i * 16 + rl) * 8;
            ah[i] = *(const bf16x8*)&AhiS[p][ai];
            al[i] = *(const bf16x8*)&AloS[p][ai];
        }
        // ---- produce chunk ch+1 into the other buffer (overlaps MFMA) ----
        if (ch + 1 < NCH) produce(p ^ 1, (ch + 1) * KC);
        // ---- 2 M-tiles x 7 N-tiles x 3 split-term MFMAs (al*bl dropped:
        //      ~2^-16 relative; round 8 measured absmax 8.0 vs 33.6 thr) ----
#pragma unroll
        for (int i = 0; i < 2; ++i)
#pragma unroll
            for (int nt = 0; nt < 7; ++nt) {
                acc[i][nt] = __builtin_amdgcn_mfma_f32_16x16x32_bf16(ah[i], bh[nt], acc[i][nt], 0, 0, 0);
                acc[i][nt] = __builtin_amdgcn_mfma_f32_16x16x32_bf16(ah[i], bl[nt], acc[i][nt], 0, 0, 0);
                acc[i][nt] = __builtin_amdgcn_mfma_f32_16x16x32_bf16(al[i], bh[nt], acc[i][nt], 0, 0, 0);
            }
        __syncthreads();             // buf[p^1] written; buf[p] reads done
    }

    // ---- epilogue (registers only; no barrier) ----
    float* ob = out + (size_t)b * OUT_PER_B;
    if (tid < NROWA) {
        ob[110 + grow] = s3;                       // level 3
        if (c3 == 0) ob[10 + g * 10 + c2] = s2;    // level 2
        if (m3 == 0) ob[g] = s1;                   // level 1
    }
    // D layout (m89-verified): col = lane&15, row = (lane>>4)*4 + reg
#pragma unroll
    for (int i = 0; i < 2; ++i) {
#pragma unroll
        for (int r = 0; r < 4; ++r) {
            const int prow = wv * 32 + i * 16 + kgl * 4 + r;
            if (prow < NROWA) {
                const int gr = q * NROWA + prow;
#pragma unroll
                for (int nt = 0; nt < 7; ++nt) {
                    const int col = nt * 16 + rl;
                    const float v = acc[i][nt][r];
                    if (col < 100)
                        ob[11110 + (size_t)gr * 100 + col] = v;   // level 5
                    else if (col < NCOLA)
                        ob[1110 + gr * 10 + (col - 100)] = v;     // level 4
                }
            }
        }
    }
}

extern "C" void kernel_launch(void* const* d_in, const int* in_sizes, int n_in,
                              void* d_out, int out_size, void* d_ws, size_t ws_size,
                              hipStream_t stream) {
    const float* path = (const float*)d_in[0];
    float* out = (float*)d_out;
    int B = in_sizes[0] / (D10 * LPATH);   // 256
    sig_kernel<<<B * 4, BLOCK, 0, stream>>>(path, out);
}